// Round 1
// baseline (6559.538 us; speedup 1.0000x reference)
//
#include <hip/hip_runtime.h>
#include <hip/hip_bf16.h>

// Problem constants (shapes fixed by reference; N/E/G derived at runtime)
#define FDIM 128
#define HDIM 128
#define ADIM 32

// ---------------------------------------------------------------------------
// deg accumulation: deg[dst] += 1 for each edge
__global__ void deg_kernel(const int* __restrict__ dst, float* __restrict__ deg, int E) {
    int e = blockIdx.x * 256 + threadIdx.x;
    if (e < E) atomicAdd(&deg[dst[e]], 1.0f);
}

// dinv[i] = (deg[i] + 1)^-0.5  (in-place on deg buffer)
__global__ void dinv_kernel(float* __restrict__ deg, int n) {
    int i = blockIdx.x * 256 + threadIdx.x;
    if (i < n) deg[i] = rsqrtf(deg[i] + 1.0f);
}

// ---------------------------------------------------------------------------
// GEMM: Out[n x 128] = X[n x 128] @ W[128 x 128]
// 32 rows per block, 256 threads, 4x4 register tile per thread.
// W staged through LDS in two 64-row halves (32 KB) + 16 KB X tile.
__global__ __launch_bounds__(256, 2) void gemm128(const float* __restrict__ X,
                                                  const float* __restrict__ W,
                                                  float* __restrict__ Out, int n) {
    __shared__ float sW[64 * 128];  // 32 KB (half of W)
    __shared__ float sX[32 * 128];  // 16 KB
    const int tid = threadIdx.x;
    const int rbase = blockIdx.x * 32;
    int rows = n - rbase; if (rows > 32) rows = 32;

    // load X tile (coalesced float4)
    {
        const float4* X4 = (const float4*)(X + (size_t)rbase * 128);
        float4* sX4 = (float4*)sX;
        for (int i = tid; i < rows * 32; i += 256) sX4[i] = X4[i];
    }

    const int tx = tid & 31;   // col group: cols 4*tx .. 4*tx+3
    const int ty = tid >> 5;   // row group: rows 4*ty .. 4*ty+3
    float acc[4][4] = {{0.f, 0.f, 0.f, 0.f}, {0.f, 0.f, 0.f, 0.f},
                       {0.f, 0.f, 0.f, 0.f}, {0.f, 0.f, 0.f, 0.f}};

    for (int half = 0; half < 2; ++half) {
        __syncthreads();  // protect sW (and cover initial sX stores)
        {
            const float4* W4 = (const float4*)(W + half * 64 * 128);
            float4* sW4 = (float4*)sW;
            for (int i = tid; i < 2048; i += 256) sW4[i] = W4[i];
        }
        __syncthreads();

        const float* xb = sX + ty * 4 * 128 + half * 64;
        #pragma unroll 8
        for (int kk = 0; kk < 64; ++kk) {
            const float4 w = *(const float4*)(sW + kk * 128 + tx * 4);
            float xv[4];
            #pragma unroll
            for (int i = 0; i < 4; ++i) xv[i] = xb[i * 128 + kk];
            #pragma unroll
            for (int i = 0; i < 4; ++i) {
                acc[i][0] = fmaf(xv[i], w.x, acc[i][0]);
                acc[i][1] = fmaf(xv[i], w.y, acc[i][1]);
                acc[i][2] = fmaf(xv[i], w.z, acc[i][2]);
                acc[i][3] = fmaf(xv[i], w.w, acc[i][3]);
            }
        }
    }

    #pragma unroll
    for (int i = 0; i < 4; ++i) {
        int r = rbase + ty * 4 + i;
        if (r < n) {
            *(float4*)(Out + (size_t)r * 128 + tx * 4) =
                make_float4(acc[i][0], acc[i][1], acc[i][2], acc[i][3]);
        }
    }
}

// ---------------------------------------------------------------------------
// Edge scatter: agg[dst] += T[src] * dinv[src]   (one thread per edge x float4)
__global__ void scatter128(const float* __restrict__ T, const int* __restrict__ src,
                           const int* __restrict__ dst, const float* __restrict__ dinv,
                           float* __restrict__ agg, int E) {
    long long gid = (long long)blockIdx.x * 256 + threadIdx.x;
    int e = (int)(gid >> 5);
    if (e >= E) return;
    int c = ((int)gid & 31) * 4;
    int s = src[e], d = dst[e];
    float sc = dinv[s];
    const float4 v = *(const float4*)(T + (size_t)s * 128 + c);
    float* ap = agg + (size_t)d * 128 + c;
    atomicAdd(ap + 0, v.x * sc);
    atomicAdd(ap + 1, v.y * sc);
    atomicAdd(ap + 2, v.z * sc);
    atomicAdd(ap + 3, v.w * sc);
}

// ---------------------------------------------------------------------------
// Epilogue: out = relu(agg*dinv + t*dinv^2 + b)   (in-place on agg is safe)
__global__ void finish128(const float* __restrict__ agg, const float* __restrict__ t,
                          const float* __restrict__ dinv, const float* __restrict__ b,
                          float* __restrict__ out, int n) {
    long long gid = (long long)blockIdx.x * 256 + threadIdx.x;
    int i = (int)(gid >> 5);
    if (i >= n) return;
    int c = ((int)gid & 31) * 4;
    float di = dinv[i];
    float di2 = di * di;
    const float4 a = *(const float4*)(agg + (size_t)i * 128 + c);
    const float4 tv = *(const float4*)(t + (size_t)i * 128 + c);
    const float4 bv = *(const float4*)(b + c);
    float4 o;
    o.x = fmaxf(a.x * di + tv.x * di2 + bv.x, 0.f);
    o.y = fmaxf(a.y * di + tv.y * di2 + bv.y, 0.f);
    o.z = fmaxf(a.z * di + tv.z * di2 + bv.z, 0.f);
    o.w = fmaxf(a.w * di + tv.w * di2 + bv.w, 0.f);
    *(float4*)(out + (size_t)i * 128 + c) = o;
}

// ---------------------------------------------------------------------------
// Mean-pool scatter: pooled[batch[i]] += h[i]; cnt[batch[i]] += 1
__global__ void pool_scatter(const float* __restrict__ h, const int* __restrict__ batch,
                             float* __restrict__ pooled, float* __restrict__ cnt, int n) {
    long long gid = (long long)blockIdx.x * 256 + threadIdx.x;
    int i = (int)(gid >> 5);
    if (i >= n) return;
    int c = ((int)gid & 31) * 4;
    int g = batch[i];
    const float4 v = *(const float4*)(h + (size_t)i * 128 + c);
    float* pp = pooled + (size_t)g * 128 + c;
    atomicAdd(pp + 0, v.x);
    atomicAdd(pp + 1, v.y);
    atomicAdd(pp + 2, v.z);
    atomicAdd(pp + 3, v.w);
    if (c == 0) atomicAdd(&cnt[g], 1.0f);
}

// ---------------------------------------------------------------------------
// Heads: action_mean = mean_pool @ Wa + ba; value = mean_pool @ Wv + bv; exp(log_std)
// out layout: [G*A action_mean][A std][G value]
__global__ void head_kernel(const float* __restrict__ pooled, const float* __restrict__ cnt,
                            const float* __restrict__ Wa, const float* __restrict__ ba,
                            const float* __restrict__ Wv, const float* __restrict__ bv,
                            const float* __restrict__ log_std, float* __restrict__ out, int G) {
    int g = blockIdx.x;
    int t = threadIdx.x;  // 64 threads
    __shared__ float sp[128];
    float inv = 1.0f / fmaxf(cnt[g], 1.0f);
    sp[t] = pooled[(size_t)g * 128 + t] * inv;
    sp[t + 64] = pooled[(size_t)g * 128 + 64 + t] * inv;
    __syncthreads();
    if (t < 32) {
        float s = 0.f;
        #pragma unroll 8
        for (int k = 0; k < 128; ++k) s = fmaf(sp[k], Wa[k * ADIM + t], s);
        out[g * ADIM + t] = s + ba[t];
        if (g == 0) out[G * ADIM + t] = expf(log_std[t]);
    } else if (t == 32) {
        float s = 0.f;
        #pragma unroll 8
        for (int k = 0; k < 128; ++k) s = fmaf(sp[k], Wv[k], s);
        out[G * ADIM + ADIM + g] = s + bv[0];
    }
}

// ---------------------------------------------------------------------------
extern "C" void kernel_launch(void* const* d_in, const int* in_sizes, int n_in,
                              void* d_out, int out_size, void* d_ws, size_t ws_size,
                              hipStream_t stream) {
    const float* x        = (const float*)d_in[0];
    const int*   ei       = (const int*)d_in[1];
    const int*   batch    = (const int*)d_in[2];
    const float* W1       = (const float*)d_in[3];
    const float* b1       = (const float*)d_in[4];
    const float* W2       = (const float*)d_in[5];
    const float* b2       = (const float*)d_in[6];
    const float* Wa       = (const float*)d_in[7];
    const float* ba       = (const float*)d_in[8];
    const float* Wv       = (const float*)d_in[9];
    const float* bv       = (const float*)d_in[10];
    const float* log_std  = (const float*)d_in[11];
    float* out = (float*)d_out;

    const int N = in_sizes[0] / FDIM;
    const int E = in_sizes[1] / 2;
    const int G = (out_size - ADIM) / (ADIM + 1);

    const int* src = ei;
    const int* dst = ei + E;

    // workspace layout (256B-aligned offsets)
    auto align = [](size_t x) { return (x + 255) & ~(size_t)255; };
    char* ws = (char*)d_ws;
    size_t off = 0;
    float* dinv = (float*)(ws + off); off = align(off + (size_t)N * 4);
    float* bufA = (float*)(ws + off); off = align(off + (size_t)N * HDIM * 4);
    float* bufB = (float*)(ws + off); off = align(off + (size_t)N * HDIM * 4);
    float* pooled = (float*)(ws + off); off = align(off + (size_t)G * HDIM * 4);
    float* cnt = (float*)(ws + off); off = align(off + (size_t)G * 4);
    (void)ws_size;

    const int blkE = (E + 255) / 256;
    const int blkN = (N + 255) / 256;
    const int blkGemm = (N + 31) / 32;
    const long long nh4 = (long long)N * 32;
    const int blkNH4 = (int)((nh4 + 255) / 256);
    const long long eh4 = (long long)E * 32;
    const int blkEH4 = (int)((eh4 + 255) / 256);

    // degree -> dinv
    hipMemsetAsync(dinv, 0, (size_t)N * 4, stream);
    deg_kernel<<<blkE, 256, 0, stream>>>(dst, dinv, E);
    dinv_kernel<<<blkN, 256, 0, stream>>>(dinv, N);

    // ---- layer 1 ----
    gemm128<<<blkGemm, 256, 0, stream>>>(x, W1, bufA, N);                 // t1 = x@W1
    hipMemsetAsync(bufB, 0, (size_t)N * HDIM * 4, stream);
    scatter128<<<blkEH4, 256, 0, stream>>>(bufA, src, dst, dinv, bufB, E);
    finish128<<<blkNH4, 256, 0, stream>>>(bufB, bufA, dinv, b1, bufB, N); // h1 in bufB

    // ---- layer 2 ----
    gemm128<<<blkGemm, 256, 0, stream>>>(bufB, W2, bufA, N);              // t2 = h1@W2
    hipMemsetAsync(bufB, 0, (size_t)N * HDIM * 4, stream);
    scatter128<<<blkEH4, 256, 0, stream>>>(bufA, src, dst, dinv, bufB, E);
    finish128<<<blkNH4, 256, 0, stream>>>(bufB, bufA, dinv, b2, bufB, N); // h2 in bufB

    // ---- pool + heads ----
    hipMemsetAsync(pooled, 0, (size_t)(G * HDIM + G) * 4 + 0, stream);
    hipMemsetAsync(cnt, 0, (size_t)G * 4, stream);
    pool_scatter<<<blkNH4, 256, 0, stream>>>(bufB, batch, pooled, cnt, N);
    head_kernel<<<G, 64, 0, stream>>>(pooled, cnt, Wa, ba, Wv, bv, log_std, out, G);
}

// Round 2
// 903.520 us; speedup vs baseline: 7.2600x; 7.2600x over previous
//
#include <hip/hip_runtime.h>
#include <hip/hip_bf16.h>

#define FDIM 128
#define HDIM 128
#define ADIM 32

// ---------------------------------------------------------------------------
// Degree count (int atomics)
__global__ void deg_count(const int* __restrict__ dst, int* __restrict__ deg, int E) {
    int e = blockIdx.x * 256 + threadIdx.x;
    if (e < E) atomicAdd(&deg[dst[e]], 1);
}

// dinv[i] = (deg[i] + 1)^-0.5
__global__ void dinv_kernel(const int* __restrict__ deg, float* __restrict__ dinv, int n) {
    int i = blockIdx.x * 256 + threadIdx.x;
    if (i < n) dinv[i] = rsqrtf((float)deg[i] + 1.0f);
}

// ---------------------------------------------------------------------------
// Exclusive scan of deg -> rowptr. 1024 items/block (256 thr x 4).
__global__ void scan1(const int* __restrict__ deg, int* __restrict__ excl,
                      int* __restrict__ bsum, int n) {
    __shared__ int tmp[256];
    const int t = threadIdx.x;
    const int idx = blockIdx.x * 1024 + t * 4;
    int v[4], s = 0;
    #pragma unroll
    for (int i = 0; i < 4; ++i) { int j = idx + i; v[i] = (j < n) ? deg[j] : 0; s += v[i]; }
    tmp[t] = s;
    __syncthreads();
    for (int off = 1; off < 256; off <<= 1) {
        int x = (t >= off) ? tmp[t - off] : 0;
        __syncthreads();
        tmp[t] += x;
        __syncthreads();
    }
    int run = tmp[t] - s;  // exclusive prefix for this thread
    #pragma unroll
    for (int i = 0; i < 4; ++i) { int j = idx + i; if (j < n) excl[j] = run; run += v[i]; }
    if (t == 255) bsum[blockIdx.x] = tmp[255];
}

// scan of block sums (nb <= 256), single block
__global__ void scan2(int* __restrict__ bsum, int nb) {
    __shared__ int tmp[256];
    const int t = threadIdx.x;
    int s = (t < nb) ? bsum[t] : 0;
    tmp[t] = s;
    __syncthreads();
    for (int off = 1; off < 256; off <<= 1) {
        int x = (t >= off) ? tmp[t - off] : 0;
        __syncthreads();
        tmp[t] += x;
        __syncthreads();
    }
    if (t < nb) bsum[t] = tmp[t] - s;  // exclusive
}

__global__ void scan3(int* __restrict__ excl, const int* __restrict__ bsum, int n, int E) {
    int i = blockIdx.x * 256 + threadIdx.x;
    if (i < n) excl[i] += bsum[blockIdx.x >> 2];  // 4 blocks of 256 per scan1 block of 1024
    if (i == 0) excl[n] = E;
}

__global__ void copy_cursor(const int* __restrict__ rowptr, int* __restrict__ cur, int n) {
    int i = blockIdx.x * 256 + threadIdx.x;
    if (i < n) cur[i] = rowptr[i];
}

__global__ void csr_fill(const int* __restrict__ src, const int* __restrict__ dst,
                         int* __restrict__ cur, int* __restrict__ col, int E) {
    int e = blockIdx.x * 256 + threadIdx.x;
    if (e >= E) return;
    int d = dst[e];
    int pos = atomicAdd(&cur[d], 1);
    col[pos] = src[e];
}

// ---------------------------------------------------------------------------
// GEMM: Out[n x 128] = X[n x 128] @ W[128 x 128]  (fp32, register-blocked)
__global__ __launch_bounds__(256, 2) void gemm128(const float* __restrict__ X,
                                                  const float* __restrict__ W,
                                                  float* __restrict__ Out, int n) {
    __shared__ float sW[64 * 128];
    __shared__ float sX[32 * 128];
    const int tid = threadIdx.x;
    const int rbase = blockIdx.x * 32;
    int rows = n - rbase; if (rows > 32) rows = 32;

    {
        const float4* X4 = (const float4*)(X + (size_t)rbase * 128);
        float4* sX4 = (float4*)sX;
        for (int i = tid; i < rows * 32; i += 256) sX4[i] = X4[i];
    }

    const int tx = tid & 31;
    const int ty = tid >> 5;
    float acc[4][4] = {{0.f,0.f,0.f,0.f},{0.f,0.f,0.f,0.f},{0.f,0.f,0.f,0.f},{0.f,0.f,0.f,0.f}};

    for (int half = 0; half < 2; ++half) {
        __syncthreads();
        {
            const float4* W4 = (const float4*)(W + half * 64 * 128);
            float4* sW4 = (float4*)sW;
            for (int i = tid; i < 2048; i += 256) sW4[i] = W4[i];
        }
        __syncthreads();

        const float* xb = sX + ty * 4 * 128 + half * 64;
        #pragma unroll 8
        for (int kk = 0; kk < 64; ++kk) {
            const float4 w = *(const float4*)(sW + kk * 128 + tx * 4);
            float xv[4];
            #pragma unroll
            for (int i = 0; i < 4; ++i) xv[i] = xb[i * 128 + kk];
            #pragma unroll
            for (int i = 0; i < 4; ++i) {
                acc[i][0] = fmaf(xv[i], w.x, acc[i][0]);
                acc[i][1] = fmaf(xv[i], w.y, acc[i][1]);
                acc[i][2] = fmaf(xv[i], w.z, acc[i][2]);
                acc[i][3] = fmaf(xv[i], w.w, acc[i][3]);
            }
        }
    }

    #pragma unroll
    for (int i = 0; i < 4; ++i) {
        int r = rbase + ty * 4 + i;
        if (r < n) {
            *(float4*)(Out + (size_t)r * 128 + tx * 4) =
                make_float4(acc[i][0], acc[i][1], acc[i][2], acc[i][3]);
        }
    }
}

// ---------------------------------------------------------------------------
// Fused CSR gather + GCN epilogue:
// out[d] = relu( (sum_{e in in(d)} T[col[e]]*dinv[col[e]]) * dinv[d]
//                + T[d]*dinv[d]^2 + bias )
// One wave per destination node; lane covers 2 of 128 cols (float2).
__global__ __launch_bounds__(256) void gather_fused(const float* __restrict__ T,
                                                    const int* __restrict__ rowptr,
                                                    const int* __restrict__ col,
                                                    const float* __restrict__ dinv,
                                                    const float* __restrict__ bias,
                                                    float* __restrict__ out, int n) {
    const int d = (blockIdx.x * 256 + threadIdx.x) >> 6;
    const int lane = threadIdx.x & 63;
    if (d >= n) return;
    const int start = rowptr[d], end = rowptr[d + 1];
    const float2* __restrict__ T2 = (const float2*)T;

    float ax = 0.f, ay = 0.f;
    int e = start;
    for (; e + 1 < end; e += 2) {
        int s0 = col[e], s1 = col[e + 1];
        float c0 = dinv[s0], c1 = dinv[s1];
        float2 v0 = T2[(size_t)s0 * 64 + lane];
        float2 v1 = T2[(size_t)s1 * 64 + lane];
        ax = fmaf(v0.x, c0, ax); ay = fmaf(v0.y, c0, ay);
        ax = fmaf(v1.x, c1, ax); ay = fmaf(v1.y, c1, ay);
    }
    if (e < end) {
        int s0 = col[e];
        float c0 = dinv[s0];
        float2 v0 = T2[(size_t)s0 * 64 + lane];
        ax = fmaf(v0.x, c0, ax); ay = fmaf(v0.y, c0, ay);
    }

    const float di = dinv[d];
    const float di2 = di * di;
    const float2 self = T2[(size_t)d * 64 + lane];
    const float2 bv = ((const float2*)bias)[lane];
    float2 o;
    o.x = fmaxf(fmaf(ax, di, fmaf(self.x, di2, bv.x)), 0.f);
    o.y = fmaxf(fmaf(ay, di, fmaf(self.y, di2, bv.y)), 0.f);
    ((float2*)out)[(size_t)d * 64 + lane] = o;
}

// ---------------------------------------------------------------------------
// batch is sorted: per-graph node ranges via binary search
__global__ void graph_bounds(const int* __restrict__ batch, int* __restrict__ gstart,
                             int n, int G) {
    int g = blockIdx.x * 128 + threadIdx.x;
    if (g > G) return;
    int lo = 0, hi = n;
    while (lo < hi) { int mid = (lo + hi) >> 1; if (batch[mid] < g) lo = mid + 1; else hi = mid; }
    gstart[g] = lo;
}

// block per graph: mean over contiguous node range (no atomics)
__global__ void pool_mean(const float* __restrict__ h, const int* __restrict__ gstart,
                          float* __restrict__ pooled, int G) {
    __shared__ float red[256];
    const int g = blockIdx.x;
    const int t = threadIdx.x;
    const int s = gstart[g], epos = gstart[g + 1];
    const int c = t & 127;
    float acc = 0.f;
    for (int r = s + (t >> 7); r < epos; r += 2) acc += h[(size_t)r * 128 + c];
    red[t] = acc;
    __syncthreads();
    if (t < 128) {
        float v = red[t] + red[t + 128];
        pooled[(size_t)g * 128 + t] = v / fmaxf((float)(epos - s), 1.0f);
    }
}

// ---------------------------------------------------------------------------
// out layout: [G*A action_mean][A std][G value]
__global__ void head_kernel(const float* __restrict__ pooled,
                            const float* __restrict__ Wa, const float* __restrict__ ba,
                            const float* __restrict__ Wv, const float* __restrict__ bv,
                            const float* __restrict__ log_std, float* __restrict__ out, int G) {
    int g = blockIdx.x;
    int t = threadIdx.x;  // 64
    __shared__ float sp[128];
    sp[t] = pooled[(size_t)g * 128 + t];
    sp[t + 64] = pooled[(size_t)g * 128 + 64 + t];
    __syncthreads();
    if (t < 32) {
        float s = 0.f;
        #pragma unroll 8
        for (int k = 0; k < 128; ++k) s = fmaf(sp[k], Wa[k * ADIM + t], s);
        out[g * ADIM + t] = s + ba[t];
        if (g == 0) out[G * ADIM + t] = expf(log_std[t]);
    } else if (t == 32) {
        float s = 0.f;
        #pragma unroll 8
        for (int k = 0; k < 128; ++k) s = fmaf(sp[k], Wv[k], s);
        out[G * ADIM + ADIM + g] = s + bv[0];
    }
}

// ---------------------------------------------------------------------------
extern "C" void kernel_launch(void* const* d_in, const int* in_sizes, int n_in,
                              void* d_out, int out_size, void* d_ws, size_t ws_size,
                              hipStream_t stream) {
    const float* x       = (const float*)d_in[0];
    const int*   ei      = (const int*)d_in[1];
    const int*   batch   = (const int*)d_in[2];
    const float* W1      = (const float*)d_in[3];
    const float* b1      = (const float*)d_in[4];
    const float* W2      = (const float*)d_in[5];
    const float* b2      = (const float*)d_in[6];
    const float* Wa      = (const float*)d_in[7];
    const float* ba      = (const float*)d_in[8];
    const float* Wv      = (const float*)d_in[9];
    const float* bv      = (const float*)d_in[10];
    const float* log_std = (const float*)d_in[11];
    float* out = (float*)d_out;

    const int N = in_sizes[0] / FDIM;
    const int E = in_sizes[1] / 2;
    const int G = (out_size - ADIM) / (ADIM + 1);

    const int* src = ei;
    const int* dst = ei + E;

    auto align = [](size_t v) { return (v + 255) & ~(size_t)255; };
    char* ws = (char*)d_ws;
    size_t off = 0;
    int*   deg_i  = (int*)(ws + off);   off = align(off + (size_t)N * 4);
    int*   rowptr = (int*)(ws + off);   off = align(off + (size_t)(N + 1) * 4);
    int*   cursor = (int*)(ws + off);   off = align(off + (size_t)N * 4);
    int*   col    = (int*)(ws + off);   off = align(off + (size_t)E * 4);
    int*   bsum   = (int*)(ws + off);   off = align(off + (size_t)256 * 4);
    int*   gstart = (int*)(ws + off);   off = align(off + (size_t)(G + 1) * 4);
    float* dinv   = (float*)(ws + off); off = align(off + (size_t)N * 4);
    float* pooled = (float*)(ws + off); off = align(off + (size_t)G * HDIM * 4);
    float* bufA   = (float*)(ws + off); off = align(off + (size_t)N * HDIM * 4);
    float* bufB   = (float*)(ws + off); off = align(off + (size_t)N * HDIM * 4);
    (void)ws_size;

    const int blkE = (E + 255) / 256;
    const int blkN = (N + 255) / 256;
    const int nb   = (N + 1023) / 1024;     // scan1 blocks (<=256)
    const int blkGemm = (N + 31) / 32;
    const int blkGather = (N * 64 + 255) / 256;  // one wave per node

    // ---- CSR build + dinv ----
    hipMemsetAsync(deg_i, 0, (size_t)N * 4, stream);
    deg_count<<<blkE, 256, 0, stream>>>(dst, deg_i, E);
    dinv_kernel<<<blkN, 256, 0, stream>>>(deg_i, dinv, N);
    scan1<<<nb, 256, 0, stream>>>(deg_i, rowptr, bsum, N);
    scan2<<<1, 256, 0, stream>>>(bsum, nb);
    scan3<<<blkN, 256, 0, stream>>>(rowptr, bsum, N, E);
    copy_cursor<<<blkN, 256, 0, stream>>>(rowptr, cursor, N);
    csr_fill<<<blkE, 256, 0, stream>>>(src, dst, cursor, col, E);

    // ---- layer 1 ----
    gemm128<<<blkGemm, 256, 0, stream>>>(x, W1, bufA, N);
    gather_fused<<<blkGather, 256, 0, stream>>>(bufA, rowptr, col, dinv, b1, bufB, N);

    // ---- layer 2 ----
    gemm128<<<blkGemm, 256, 0, stream>>>(bufB, W2, bufA, N);
    gather_fused<<<blkGather, 256, 0, stream>>>(bufA, rowptr, col, dinv, b2, bufB, N);

    // ---- pool + heads ----
    graph_bounds<<<1, 128, 0, stream>>>(batch, gstart, N, G);
    pool_mean<<<G, 256, 0, stream>>>(bufB, gstart, pooled, G);
    head_kernel<<<G, 64, 0, stream>>>(pooled, Wa, ba, Wv, bv, log_std, out, G);
}

// Round 3
// 680.785 us; speedup vs baseline: 9.6353x; 1.3272x over previous
//
#include <hip/hip_runtime.h>
#include <hip/hip_bf16.h>

#define FDIM 128
#define HDIM 128
#define ADIM 32
#define PCH 128   // rows per pool block

// ---------------------------------------------------------------------------
__global__ void deg_count(const int* __restrict__ dst, int* __restrict__ deg, int E) {
    int e = blockIdx.x * 256 + threadIdx.x;
    if (e < E) atomicAdd(&deg[dst[e]], 1);
}

__global__ void dinv_kernel(const int* __restrict__ deg, float* __restrict__ dinv, int n) {
    int i = blockIdx.x * 256 + threadIdx.x;
    if (i < n) dinv[i] = rsqrtf((float)deg[i] + 1.0f);
}

// ---------------------------------------------------------------------------
// Exclusive scan of deg -> rowptr. 1024 items/block (256 thr x 4).
__global__ void scan1(const int* __restrict__ deg, int* __restrict__ excl,
                      int* __restrict__ bsum, int n) {
    __shared__ int tmp[256];
    const int t = threadIdx.x;
    const int idx = blockIdx.x * 1024 + t * 4;
    int v[4], s = 0;
    #pragma unroll
    for (int i = 0; i < 4; ++i) { int j = idx + i; v[i] = (j < n) ? deg[j] : 0; s += v[i]; }
    tmp[t] = s;
    __syncthreads();
    for (int off = 1; off < 256; off <<= 1) {
        int x = (t >= off) ? tmp[t - off] : 0;
        __syncthreads();
        tmp[t] += x;
        __syncthreads();
    }
    int run = tmp[t] - s;
    #pragma unroll
    for (int i = 0; i < 4; ++i) { int j = idx + i; if (j < n) excl[j] = run; run += v[i]; }
    if (t == 255) bsum[blockIdx.x] = tmp[255];
}

__global__ void scan2(int* __restrict__ bsum, int nb) {
    __shared__ int tmp[256];
    const int t = threadIdx.x;
    int s = (t < nb) ? bsum[t] : 0;
    tmp[t] = s;
    __syncthreads();
    for (int off = 1; off < 256; off <<= 1) {
        int x = (t >= off) ? tmp[t - off] : 0;
        __syncthreads();
        tmp[t] += x;
        __syncthreads();
    }
    if (t < nb) bsum[t] = tmp[t] - s;
}

__global__ void scan3(int* __restrict__ excl, const int* __restrict__ bsum, int n, int E) {
    int i = blockIdx.x * 256 + threadIdx.x;
    if (i < n) excl[i] += bsum[blockIdx.x >> 2];
    if (i == 0) excl[n] = E;
}

__global__ void copy_cursor(const int* __restrict__ rowptr, int* __restrict__ cur, int n) {
    int i = blockIdx.x * 256 + threadIdx.x;
    if (i < n) cur[i] = rowptr[i];
}

__global__ void csr_fill(const int* __restrict__ src, const int* __restrict__ dst,
                         int* __restrict__ cur, int* __restrict__ col, int E) {
    int e = blockIdx.x * 256 + threadIdx.x;
    if (e >= E) return;
    int d = dst[e];
    int pos = atomicAdd(&cur[d], 1);
    col[pos] = src[e];
}

// ---------------------------------------------------------------------------
// GEMM + row-scale epilogue: Out[r] = (X[r] @ W) * rowscale[r]
__global__ __launch_bounds__(256, 2) void gemm128(const float* __restrict__ X,
                                                  const float* __restrict__ W,
                                                  const float* __restrict__ rowscale,
                                                  float* __restrict__ Out, int n) {
    __shared__ float sW[64 * 128];
    __shared__ float sX[32 * 128];
    const int tid = threadIdx.x;
    const int rbase = blockIdx.x * 32;
    int rows = n - rbase; if (rows > 32) rows = 32;

    {
        const float4* X4 = (const float4*)(X + (size_t)rbase * 128);
        float4* sX4 = (float4*)sX;
        for (int i = tid; i < rows * 32; i += 256) sX4[i] = X4[i];
    }

    const int tx = tid & 31;
    const int ty = tid >> 5;
    float acc[4][4] = {{0.f,0.f,0.f,0.f},{0.f,0.f,0.f,0.f},{0.f,0.f,0.f,0.f},{0.f,0.f,0.f,0.f}};

    for (int half = 0; half < 2; ++half) {
        __syncthreads();
        {
            const float4* W4 = (const float4*)(W + half * 64 * 128);
            float4* sW4 = (float4*)sW;
            for (int i = tid; i < 2048; i += 256) sW4[i] = W4[i];
        }
        __syncthreads();

        const float* xb = sX + ty * 4 * 128 + half * 64;
        #pragma unroll 8
        for (int kk = 0; kk < 64; ++kk) {
            const float4 w = *(const float4*)(sW + kk * 128 + tx * 4);
            float xv[4];
            #pragma unroll
            for (int i = 0; i < 4; ++i) xv[i] = xb[i * 128 + kk];
            #pragma unroll
            for (int i = 0; i < 4; ++i) {
                acc[i][0] = fmaf(xv[i], w.x, acc[i][0]);
                acc[i][1] = fmaf(xv[i], w.y, acc[i][1]);
                acc[i][2] = fmaf(xv[i], w.z, acc[i][2]);
                acc[i][3] = fmaf(xv[i], w.w, acc[i][3]);
            }
        }
    }

    #pragma unroll
    for (int i = 0; i < 4; ++i) {
        int r = rbase + ty * 4 + i;
        if (r < n) {
            float sc = rowscale[r];
            *(float4*)(Out + (size_t)r * 128 + tx * 4) =
                make_float4(acc[i][0] * sc, acc[i][1] * sc, acc[i][2] * sc, acc[i][3] * sc);
        }
    }
}

// ---------------------------------------------------------------------------
// Fused CSR gather + epilogue on pre-scaled T' = (X@W)*dinv[row]:
//   out[d] = relu( (sum_{s in in(d)} T'[s] + T'[d]) * dinv[d] + bias )
// One wave per destination node; lane covers 2 of 128 cols.
__global__ __launch_bounds__(256) void gather_fused(const float* __restrict__ T,
                                                    const int* __restrict__ rowptr,
                                                    const int* __restrict__ col,
                                                    const float* __restrict__ dinv,
                                                    const float* __restrict__ bias,
                                                    float* __restrict__ out, int n) {
    const int d = (blockIdx.x * 256 + threadIdx.x) >> 6;
    const int lane = threadIdx.x & 63;
    if (d >= n) return;
    int e = rowptr[d];
    const int end = rowptr[d + 1];
    const float2* __restrict__ T2 = (const float2*)T;

    float ax = 0.f, ay = 0.f, bx = 0.f, by = 0.f;
    for (; e + 3 < end; e += 4) {
        int s0 = col[e], s1 = col[e + 1], s2 = col[e + 2], s3 = col[e + 3];
        float2 v0 = T2[(size_t)s0 * 64 + lane];
        float2 v1 = T2[(size_t)s1 * 64 + lane];
        float2 v2 = T2[(size_t)s2 * 64 + lane];
        float2 v3 = T2[(size_t)s3 * 64 + lane];
        ax += v0.x + v1.x; ay += v0.y + v1.y;
        bx += v2.x + v3.x; by += v2.y + v3.y;
    }
    for (; e < end; ++e) {
        int s = col[e];
        float2 v = T2[(size_t)s * 64 + lane];
        ax += v.x; ay += v.y;
    }

    const float2 self = T2[(size_t)d * 64 + lane];
    const float di = dinv[d];
    const float2 bv = ((const float2*)bias)[lane];
    float2 o;
    o.x = fmaxf(fmaf(ax + bx + self.x, di, bv.x), 0.f);
    o.y = fmaxf(fmaf(ay + by + self.y, di, bv.y), 0.f);
    ((float2*)out)[(size_t)d * 64 + lane] = o;
}

// ---------------------------------------------------------------------------
__global__ void graph_bounds(const int* __restrict__ batch, int* __restrict__ gstart,
                             int n, int G) {
    int g = blockIdx.x * 128 + threadIdx.x;
    if (g > G) return;
    int lo = 0, hi = n;
    while (lo < hi) { int mid = (lo + hi) >> 1; if (batch[mid] < g) lo = mid + 1; else hi = mid; }
    gstart[g] = lo;
}

// Parallel partial-sum pool: block handles PCH contiguous rows; batch is sorted
// so each thread keeps one running accumulator, flushing on graph change.
__global__ __launch_bounds__(256) void pool_partial(const float* __restrict__ h,
                                                    const int* __restrict__ batch,
                                                    float* __restrict__ pooled, int n) {
    const int c = threadIdx.x & 127;
    const int half = threadIdx.x >> 7;
    int r = blockIdx.x * PCH + half;
    int rend = blockIdx.x * PCH + PCH;
    if (rend > n) rend = n;
    float acc = 0.f;
    int cur = -1;
    for (; r < rend; r += 2) {
        int g = batch[r];
        if (g != cur) {
            if (cur >= 0) atomicAdd(&pooled[(size_t)cur * 128 + c], acc);
            acc = 0.f;
            cur = g;
        }
        acc += h[(size_t)r * 128 + c];
    }
    if (cur >= 0) atomicAdd(&pooled[(size_t)cur * 128 + c], acc);
}

// ---------------------------------------------------------------------------
// out layout: [G*A action_mean][A std][G value]; divides pooled sums by count
__global__ void head_kernel(const float* __restrict__ pooled, const int* __restrict__ gstart,
                            const float* __restrict__ Wa, const float* __restrict__ ba,
                            const float* __restrict__ Wv, const float* __restrict__ bv,
                            const float* __restrict__ log_std, float* __restrict__ out, int G) {
    int g = blockIdx.x;
    int t = threadIdx.x;  // 64
    __shared__ float sp[128];
    float inv = 1.0f / fmaxf((float)(gstart[g + 1] - gstart[g]), 1.0f);
    sp[t] = pooled[(size_t)g * 128 + t] * inv;
    sp[t + 64] = pooled[(size_t)g * 128 + 64 + t] * inv;
    __syncthreads();
    if (t < 32) {
        float s = 0.f;
        #pragma unroll 8
        for (int k = 0; k < 128; ++k) s = fmaf(sp[k], Wa[k * ADIM + t], s);
        out[g * ADIM + t] = s + ba[t];
        if (g == 0) out[G * ADIM + t] = expf(log_std[t]);
    } else if (t == 32) {
        float s = 0.f;
        #pragma unroll 8
        for (int k = 0; k < 128; ++k) s = fmaf(sp[k], Wv[k], s);
        out[G * ADIM + ADIM + g] = s + bv[0];
    }
}

// ---------------------------------------------------------------------------
extern "C" void kernel_launch(void* const* d_in, const int* in_sizes, int n_in,
                              void* d_out, int out_size, void* d_ws, size_t ws_size,
                              hipStream_t stream) {
    const float* x       = (const float*)d_in[0];
    const int*   ei      = (const int*)d_in[1];
    const int*   batch   = (const int*)d_in[2];
    const float* W1      = (const float*)d_in[3];
    const float* b1      = (const float*)d_in[4];
    const float* W2      = (const float*)d_in[5];
    const float* b2      = (const float*)d_in[6];
    const float* Wa      = (const float*)d_in[7];
    const float* ba      = (const float*)d_in[8];
    const float* Wv      = (const float*)d_in[9];
    const float* bv      = (const float*)d_in[10];
    const float* log_std = (const float*)d_in[11];
    float* out = (float*)d_out;

    const int N = in_sizes[0] / FDIM;
    const int E = in_sizes[1] / 2;
    const int G = (out_size - ADIM) / (ADIM + 1);

    const int* src = ei;
    const int* dst = ei + E;

    auto align = [](size_t v) { return (v + 255) & ~(size_t)255; };
    char* ws = (char*)d_ws;
    size_t off = 0;
    int*   deg_i  = (int*)(ws + off);   off = align(off + (size_t)N * 4);
    int*   rowptr = (int*)(ws + off);   off = align(off + (size_t)(N + 1) * 4);
    int*   cursor = (int*)(ws + off);   off = align(off + (size_t)N * 4);
    int*   col    = (int*)(ws + off);   off = align(off + (size_t)E * 4);
    int*   bsum   = (int*)(ws + off);   off = align(off + (size_t)256 * 4);
    int*   gstart = (int*)(ws + off);   off = align(off + (size_t)(G + 1) * 4);
    float* dinv   = (float*)(ws + off); off = align(off + (size_t)N * 4);
    float* pooled = (float*)(ws + off); off = align(off + (size_t)G * HDIM * 4);
    float* bufA   = (float*)(ws + off); off = align(off + (size_t)N * HDIM * 4);
    float* bufB   = (float*)(ws + off); off = align(off + (size_t)N * HDIM * 4);
    (void)ws_size;

    const int blkE = (E + 255) / 256;
    const int blkN = (N + 255) / 256;
    const int nb   = (N + 1023) / 1024;
    const int blkGemm = (N + 31) / 32;
    const int blkGather = (N * 64 + 255) / 256;
    const int blkPool = (N + PCH - 1) / PCH;

    // ---- CSR build + dinv ----
    hipMemsetAsync(deg_i, 0, (size_t)N * 4, stream);
    deg_count<<<blkE, 256, 0, stream>>>(dst, deg_i, E);
    dinv_kernel<<<blkN, 256, 0, stream>>>(deg_i, dinv, N);
    scan1<<<nb, 256, 0, stream>>>(deg_i, rowptr, bsum, N);
    scan2<<<1, 256, 0, stream>>>(bsum, nb);
    scan3<<<blkN, 256, 0, stream>>>(rowptr, bsum, N, E);
    copy_cursor<<<blkN, 256, 0, stream>>>(rowptr, cursor, N);
    csr_fill<<<blkE, 256, 0, stream>>>(src, dst, cursor, col, E);
    graph_bounds<<<1, 128, 0, stream>>>(batch, gstart, N, G);

    // ---- layer 1 ----
    gemm128<<<blkGemm, 256, 0, stream>>>(x, W1, dinv, bufA, N);
    gather_fused<<<blkGather, 256, 0, stream>>>(bufA, rowptr, col, dinv, b1, bufB, N);

    // ---- layer 2 ----
    gemm128<<<blkGemm, 256, 0, stream>>>(bufB, W2, dinv, bufA, N);
    gather_fused<<<blkGather, 256, 0, stream>>>(bufA, rowptr, col, dinv, b2, bufB, N);

    // ---- pool + heads ----
    hipMemsetAsync(pooled, 0, (size_t)G * HDIM * 4, stream);
    pool_partial<<<blkPool, 256, 0, stream>>>(bufB, batch, pooled, N);
    head_kernel<<<G, 64, 0, stream>>>(pooled, gstart, Wa, ba, Wv, bv, log_std, out, G);
}